// Round 7
// baseline (300.695 us; speedup 1.0000x reference)
//
#include <hip/hip_runtime.h>
#include <math.h>

// Problem constants (from reference): B=4096, D=784, H=16, L=4, R=4, K=8
constexpr int cB   = 4096;
constexpr int cD   = 784;
constexpr int cD1  = 392;
constexpr int cH   = 16;
constexpr int cL   = 4;
constexpr int cR   = 4;
constexpr int cDIN = 1176;            // D1 + D
constexpr int cPDIM = cD1 * 3 * 8;    // 9408 = D1 * 3K
#define LOG2PI_F 1.8378770664093453f
#define L2E_F    1.4426950408889634f   // log2(e)
#define LN2_F    0.6931471805599453f   // ln(2)
#define LN_LN2_F (-0.36651292058166432701f) // ln(ln 2)

__device__ __forceinline__ float rcpf(float x)  { return __builtin_amdgcn_rcpf(x); }
__device__ __forceinline__ float exp2f_(float x){ return __builtin_amdgcn_exp2f(x); }
__device__ __forceinline__ float log2f_(float x){ return __builtin_amdgcn_logf(x); }
__device__ __forceinline__ float expn(float x)  { return exp2f_(x * L2E_F); }   // e^x
__device__ __forceinline__ float logn(float x)  { return log2f_(x) * LN2_F; }   // ln x

typedef __attribute__((ext_vector_type(2))) float f32x2;  // -> v_pk_*_f32

// h[16][b] (transposed) = conditioner MLP on concat(zb, x).
// 4 samples / block (4 waves), split-K=4.  do_init (l=3 only) seeds logq.
__global__ void __launch_bounds__(256, 4) mlp_kernel(
    const float* __restrict__ zbsrc, const float* __restrict__ x,
    const float* __restrict__ Win, const float* __restrict__ bin,
    const float* __restrict__ W1, const float* __restrict__ b1,
    const float* __restrict__ W2, const float* __restrict__ b2,
    float* __restrict__ hbuf,
    const float* __restrict__ eps, float* __restrict__ logq, int do_init)
{
    __shared__ float part[4][4][16];   // [kchunk][sample][col]
    const int wid  = threadIdx.x >> 6;
    const int lane = threadIdx.x & 63;
    const int j = lane & 15;
    const int G = lane >> 4;                      // 16-lane group 0..3
    const int bs = blockIdx.x * 4;                // block's 4 samples
    const int r0 = wid * 294;                     // wave's row range start

    if (do_init) {   // fold old init_kernel: wave w handles sample bs+w
        const int b = bs + wid;
        const float4* e = (const float4*)(eps + (size_t)b * cD);
        float sum = 0.f;
        for (int i = lane; i < cD / 4; i += 64) {   // 784 = 196 float4
            float4 v = e[i];
            sum = fmaf(v.x, v.x, sum); sum = fmaf(v.y, v.y, sum);
            sum = fmaf(v.z, v.z, sum); sum = fmaf(v.w, v.w, sum);
        }
        #pragma unroll
        for (int off = 32; off; off >>= 1) sum += __shfl_xor(sum, off, 64);
        if (lane == 0) logq[b] = -0.5f * sum - 0.5f * (float)cD * LOG2PI_F;
    }

    float acc[4][16];
    #pragma unroll
    for (int s = 0; s < 4; ++s)
        #pragma unroll
        for (int c = 0; c < 16; ++c) acc[s][c] = 0.f;

    const float* pz[4]; const float* px[4];
    #pragma unroll
    for (int s = 0; s < 4; ++s) {
        pz[s] = zbsrc + (size_t)(bs + s) * cD;
        px[s] = x + (size_t)(bs + s) * cD - cD1;   // valid for i>=cD1
    }

    for (int i = r0 + lane; i < r0 + 294; i += 64) {
        const float4* wr = (const float4*)(Win + (size_t)i * cH);
        float4 w0 = wr[0], w1 = wr[1], w2 = wr[2], w3 = wr[3];
        float wv[16] = {w0.x,w0.y,w0.z,w0.w, w1.x,w1.y,w1.z,w1.w,
                        w2.x,w2.y,w2.z,w2.w, w3.x,w3.y,w3.z,w3.w};
        #pragma unroll
        for (int s = 0; s < 4; ++s) {
            const float* src = (i < cD1) ? pz[s] : px[s];
            float v = src[i];
            #pragma unroll
            for (int c = 0; c < 16; ++c) acc[s][c] = fmaf(v, wv[c], acc[s][c]);
        }
    }

    // Per-sample transpose-reduce (stages 8,4,2,1).
    #pragma unroll
    for (int s = 0; s < 4; ++s) {
        #pragma unroll
        for (int c = 0; c < 8; ++c) {
            float sent = (lane & 8) ? acc[s][c] : acc[s][c + 8];
            float mine = (lane & 8) ? acc[s][c + 8] : acc[s][c];
            acc[s][c] = mine + __shfl_xor(sent, 8, 64);
        }
        #pragma unroll
        for (int c = 0; c < 4; ++c) {
            float sent = (lane & 4) ? acc[s][c] : acc[s][c + 4];
            float mine = (lane & 4) ? acc[s][c + 4] : acc[s][c];
            acc[s][c] = mine + __shfl_xor(sent, 4, 64);
        }
        #pragma unroll
        for (int c = 0; c < 2; ++c) {
            float sent = (lane & 2) ? acc[s][c] : acc[s][c + 2];
            float mine = (lane & 2) ? acc[s][c + 2] : acc[s][c];
            acc[s][c] = mine + __shfl_xor(sent, 2, 64);
        }
        {
            float sent = (lane & 1) ? acc[s][0] : acc[s][1];
            float mine = (lane & 1) ? acc[s][1] : acc[s][0];
            acc[s][0] = mine + __shfl_xor(sent, 1, 64);
        }
    }
    const int g4 = (lane >> 4) & 1, g5 = (lane >> 5) & 1;
    float a01, a23, colsum;
    {
        float sent = g4 ? acc[0][0] : acc[1][0];
        float keep = g4 ? acc[1][0] : acc[0][0];
        a01 = keep + __shfl_xor(sent, 16, 64);
    }
    {
        float sent = g4 ? acc[2][0] : acc[3][0];
        float keep = g4 ? acc[3][0] : acc[2][0];
        a23 = keep + __shfl_xor(sent, 16, 64);
    }
    {
        float sent = g5 ? a01 : a23;
        float keep = g5 ? a23 : a01;
        colsum = keep + __shfl_xor(sent, 32, 64);   // group G owns sample G
    }

    part[wid][G][j] = colsum;
    __syncthreads();
    if (wid != 0) return;

    colsum = part[0][G][j] + part[1][G][j] + part[2][G][j] + part[3][G][j];

    float t0 = colsum + bin[j];
    float hj = t0 * rcpf(1.0f + expn(-t0));   // square_swish

    #pragma unroll
    for (int r = 0; r < cR; ++r) {
        const float* w1r = W1 + r * 256;
        const float* w2r = W2 + r * 256;
        float u = b1[r * 16 + j];
        #pragma unroll
        for (int i = 0; i < 16; ++i)
            u = fmaf(__shfl(hj, i, 16), w1r[i * 16 + j], u);
        u = u * rcpf(1.0f + expn(-u));
        float v = b2[r * 16 + j];
        #pragma unroll
        for (int i = 0; i < 16; ++i)
            v = fmaf(__shfl(u, i, 16), w2r[i * 16 + j], v);
        hj += v;
    }
    hbuf[(size_t)j * cB + (bs + G)] = hj;   // transposed: [16][B]
}

// Self-contained single-item solver (rare path: pair had a yb>30 member).
// Recomputes its own projection from global memory; body is the r4/r6
// per-item code verbatim (bitwise identical per item).
__device__ void solve_full(int b, int d, float y0,
                           const float* __restrict__ hbuf,
                           const float* __restrict__ Wo,
                           const float* __restrict__ bo,
                           float& xv_out, float& ld_out, float& sgn_out)
{
    float hh[16];
    #pragma unroll
    for (int i = 0; i < 16; ++i) hh[i] = hbuf[(size_t)i * cB + b];

    f32x2 P[12];
    {
        const f32x2* bp = (const f32x2*)(bo + (size_t)d * 24);
        #pragma unroll
        for (int j2 = 0; j2 < 12; ++j2) P[j2] = bp[j2];
        #pragma unroll
        for (int i = 0; i < 16; ++i) {
            const f32x2 hv2 = {hh[i], hh[i]};
            const float4* wr = (const float4*)(Wo + (size_t)i * cPDIM + (size_t)d * 24);
            #pragma unroll
            for (int q = 0; q < 6; ++q) {
                float4 wv = wr[q];
                f32x2 wa = {wv.x, wv.y};
                f32x2 wb = {wv.z, wv.w};
                P[2*q]   = __builtin_elementwise_fma(hv2, wa, P[2*q]);
                P[2*q+1] = __builtin_elementwise_fma(hv2, wb, P[2*q+1]);
            }
        }
    }

    const float sgn = (y0 < 0.f) ? -1.f : 1.f;
    const float yb  = fabsf(y0);
    sgn_out = sgn;

    f32x2 pm2[4], q22[4], wt2[4], is22[4], nm22[4];
    float S, lgSn, SLN2, lo, hi, x0;
    {
        float m = P[0][0];
        #pragma unroll
        for (int k = 1; k < 8; ++k) m = fmaxf(m, P[k >> 1][k & 1]);
        S = 0.f;
        #pragma unroll
        for (int k = 0; k < 8; ++k) {
            float pmv = P[k >> 1][k & 1] - m;
            float wtv = exp2f_(pmv * L2E_F);
            pm2[k >> 1][k & 1] = pmv;
            wt2[k >> 1][k & 1] = wtv;
            S += wtv;
        }
        lgSn = log2f_(S) * LN2_F;
        SLN2 = S * LN2_F;
        float lo0 = 1e30f, hi0 = -1e30f, xa = 0.f;
        #pragma unroll
        for (int k = 0; k < 8; ++k) {
            float q2v = P[8 + (k >> 1)][k & 1] * L2E_F;
            float sk  = exp2f_(q2v);
            float ik  = exp2f_(-q2v);
            float is2v = ik * L2E_F;
            float mub = sgn * P[4 + (k >> 1)][k & 1];
            q22[k >> 1][k & 1]  = q2v;
            is22[k >> 1][k & 1] = is2v;
            nm22[k >> 1][k & 1] = -mub * is2v;
            float wtv = wt2[k >> 1][k & 1];
            float inv = fmaf(yb, sk, mub);
            lo0 = fminf(lo0, inv); hi0 = fmaxf(hi0, inv);
            xa = fmaf(wtv, inv, xa);
        }
        float pad = 1e-3f + 1e-5f * (fabsf(lo0) + fabsf(hi0));
        lo = lo0 - pad; hi = hi0 + pad;
        x0 = xa * rcpf(S);
    }

    float xv, ld;
    if (yb <= 30.0f) {
        xv = x0;
        #pragma unroll 1
        for (int it = 0; it < 3; ++it) {
            f32x2 xv2 = {xv, xv};
            f32x2 sfv2 = {0.f, 0.f}, pdfa2 = {0.f, 0.f};
            #pragma unroll
            for (int kk = 0; kk < 4; ++kk) {
                f32x2 t2 = __builtin_elementwise_fma(xv2, is22[kk], nm22[kk]);
                f32x2 e1;
                e1.x = 1.0f + exp2f_(t2.x);
                e1.y = 1.0f + exp2f_(t2.y);
                f32x2 r = { rcpf(e1.x), rcpf(e1.y) };
                sfv2  = __builtin_elementwise_fma(wt2[kk], r, sfv2);
                f32x2 rr = __builtin_elementwise_fma(-r, r, r);
                f32x2 wis2v = wt2[kk] * is22[kk];
                pdfa2 = __builtin_elementwise_fma(wis2v, rr, pdfa2);
            }
            float sfv = sfv2.x + sfv2.y;
            float pdfa = pdfa2.x + pdfa2.y;
            float cdf = S - sfv;
            float f = (log2f_(cdf) - log2f_(sfv)) * LN2_F;
            if (f < yb) lo = xv; else hi = xv;
            float step = (f - yb) * cdf * sfv * rcpf(pdfa * SLN2);
            float xn = xv - step;
            if (!(xn > lo && xn < hi)) xn = 0.5f * (lo + hi);
            xv = xn;
        }
        {
            f32x2 xv2 = {xv, xv};
            f32x2 sfv2 = {0.f, 0.f}, pdfa2 = {0.f, 0.f};
            #pragma unroll
            for (int kk = 0; kk < 4; ++kk) {
                f32x2 t2 = __builtin_elementwise_fma(xv2, is22[kk], nm22[kk]);
                f32x2 e1;
                e1.x = 1.0f + exp2f_(t2.x);
                e1.y = 1.0f + exp2f_(t2.y);
                f32x2 r = { rcpf(e1.x), rcpf(e1.y) };
                sfv2  = __builtin_elementwise_fma(wt2[kk], r, sfv2);
                f32x2 rr = __builtin_elementwise_fma(-r, r, r);
                f32x2 wis2v = wt2[kk] * is22[kk];
                pdfa2 = __builtin_elementwise_fma(wis2v, rr, pdfa2);
            }
            float sfv = sfv2.x + sfv2.y;
            float pdfa = pdfa2.x + pdfa2.y;
            float cdf = S - sfv;
            float l2c = log2f_(cdf), l2s = log2f_(sfv), l2p = log2f_(pdfa);
            ld = (l2p - l2c - l2s) * LN2_F + LN_LN2_F + lgSn;
            float f = (l2c - l2s) * LN2_F;
            if (f < yb) lo = xv; else hi = xv;
            float step = (f - yb) * cdf * sfv * rcpf(pdfa * SLN2);
            float xn = xv - step;
            if (!(xn > lo && xn < hi)) xn = 0.5f * (lo + hi);
            xv = xn;
        }
    } else {
        xv = x0;
        #pragma unroll 1
        for (int it = 0; it < 4; ++it) {
            float u[8];
            float mu_ = -1e30f;
            #pragma unroll
            for (int k = 0; k < 8; ++k) {
                float is2v = is22[k >> 1][k & 1];
                float nm2v = nm22[k >> 1][k & 1];
                float lwv  = pm2[k >> 1][k & 1] - lgSn;
                float t  = fmaf(xv, is2v, nm2v) * LN2_F;
                float ec = fminf(expn(-t), 1.0f);
                u[k] = lwv - t - ec * fmaf(-0.5f, ec, 1.0f);
                mu_ = fmaxf(mu_, u[k]);
            }
            float Su = 0.f;
            #pragma unroll
            for (int k = 0; k < 8; ++k) Su += expn(u[k] - mu_);
            float lsf = mu_ + logn(Su);
            float m2 = -1e30f;
            #pragma unroll
            for (int k = 0; k < 8; ++k) m2 = fmaxf(m2, u[k] - q22[k >> 1][k & 1] * LN2_F);
            float S2 = 0.f;
            #pragma unroll
            for (int k = 0; k < 8; ++k) S2 += expn(u[k] - q22[k >> 1][k & 1] * LN2_F - m2);
            float lp = m2 + logn(S2);
            if (it == 3) { ld = lp - lsf; break; }
            float f = -lsf;
            if (f < yb) lo = xv; else hi = xv;
            float step = (f - yb) * expn(lsf - lp);
            float xn = xv - step;
            if (!(xn > lo && xn < hi)) xn = 0.5f * (lo + hi);
            xv = xn;
        }
    }
    xv_out = xv;
    ld_out = ld;
}

// Invert the logistic-mixture logit per (sample b, dim d).
// v9: TWO items per thread (ILP).  r0-r6 established: per-wave wall ~22k cyc
// vs ~2.7k issue cyc — the kernel is dependency-latency-bound with only ~5
// solver chains/SIMD resident (r6: removing all VMEM made it WORSE, so not
// memory).  Fix the invariant nobody touched: chains in flight.  Each thread
// solves (b,d) and (b+64,d): Wo/bo register-shared (amortized 2x), the two
// chains are independent and interleave in every unrolled m-loop.  Per-item
// op order is UNCHANGED -> z/ld bitwise identical.  Rare yb>30 pair member
// falls back to solve_full (self-contained, never taken on this data).
__global__ void __launch_bounds__(256) invert_kernel(
    float* __restrict__ z, const float* __restrict__ ysrc,
    const float* __restrict__ hbuf,
    const float* __restrict__ Wo, const float* __restrict__ bo,
    float* __restrict__ logq, int za_off)
{
    __shared__ float red[2][256];
    const int wid  = threadIdx.x >> 6;
    const int lane = threadIdx.x & 63;
    const int d = __builtin_amdgcn_readfirstlane(blockIdx.x * 4 + wid); // uniform
    const int b0 = blockIdx.y * 128;
    const int b[2] = { b0 + lane, b0 + 64 + lane };

    // hh for both items: coalesced, all issued up front
    float hh[2][16];
    #pragma unroll
    for (int i = 0; i < 16; ++i) {
        hh[0][i] = hbuf[(size_t)i * cB + b[0]];
        hh[1][i] = hbuf[(size_t)i * cB + b[1]];
    }
    float y0[2];
    y0[0] = ysrc[(size_t)b[0] * cD + za_off + d];
    y0[1] = ysrc[(size_t)b[1] * cD + za_off + d];

    // Fused projection: Wo float4 regs shared by both items' packed FMAs.
    f32x2 P[2][12];
    {
        const f32x2* bp = (const f32x2*)(bo + (size_t)d * 24);
        #pragma unroll
        for (int j2 = 0; j2 < 12; ++j2) { P[0][j2] = bp[j2]; P[1][j2] = P[0][j2]; }
        #pragma unroll
        for (int i = 0; i < 16; ++i) {
            const float4* wr = (const float4*)(Wo + (size_t)i * cPDIM + (size_t)d * 24);
            float4 w[6];
            #pragma unroll
            for (int q = 0; q < 6; ++q) w[q] = wr[q];
            #pragma unroll
            for (int m = 0; m < 2; ++m) {
                const f32x2 hv2 = {hh[m][i], hh[m][i]};
                #pragma unroll
                for (int q = 0; q < 6; ++q) {
                    f32x2 wa = {w[q].x, w[q].y};
                    f32x2 wb = {w[q].z, w[q].w};
                    P[m][2*q]   = __builtin_elementwise_fma(hv2, wa, P[m][2*q]);
                    P[m][2*q+1] = __builtin_elementwise_fma(hv2, wb, P[m][2*q+1]);
                }
            }
        }
    }

    float sgn[2], yb[2];
    #pragma unroll
    for (int m = 0; m < 2; ++m) {
        sgn[m] = (y0[m] < 0.f) ? -1.f : 1.f;
        yb[m]  = fabsf(y0[m]);
    }

    float xv[2], ld[2];
    const bool fast = (yb[0] <= 30.0f) && (yb[1] <= 30.0f);
    if (fast) {
        // Fused setup (per-item op order = r6's setup exactly).
        f32x2 wt2[2][4], is22[2][4], nm22[2][4];
        float S[2], lgSn[2], SLN2[2], lo[2], hi[2];
        #pragma unroll
        for (int m = 0; m < 2; ++m) {
            float mx = P[m][0][0];
            #pragma unroll
            for (int k = 1; k < 8; ++k) mx = fmaxf(mx, P[m][k >> 1][k & 1]);
            float Sv = 0.f;
            #pragma unroll
            for (int k = 0; k < 8; ++k) {
                float pmv = P[m][k >> 1][k & 1] - mx;
                float wtv = exp2f_(pmv * L2E_F);
                wt2[m][k >> 1][k & 1] = wtv;
                Sv += wtv;
            }
            S[m] = Sv;
            lgSn[m] = log2f_(Sv) * LN2_F;
            SLN2[m] = Sv * LN2_F;
            float lo0 = 1e30f, hi0 = -1e30f, xa = 0.f;
            #pragma unroll
            for (int k = 0; k < 8; ++k) {
                float q2v = P[m][8 + (k >> 1)][k & 1] * L2E_F;
                float sk  = exp2f_(q2v);
                float ik  = exp2f_(-q2v);
                float is2v = ik * L2E_F;
                float mub = sgn[m] * P[m][4 + (k >> 1)][k & 1];
                is22[m][k >> 1][k & 1] = is2v;
                nm22[m][k >> 1][k & 1] = -mub * is2v;
                float wtv = wt2[m][k >> 1][k & 1];
                float inv = fmaf(yb[m], sk, mub);
                lo0 = fminf(lo0, inv); hi0 = fmaxf(hi0, inv);
                xa = fmaf(wtv, inv, xa);
            }
            float pad = 1e-3f + 1e-5f * (fabsf(lo0) + fabsf(hi0));
            lo[m] = lo0 - pad; hi[m] = hi0 + pad;
            xv[m] = xa * rcpf(S[m]);
        }

        // Fused main loop: both chains' evals in one iteration body.
        #pragma unroll 1
        for (int it = 0; it < 3; ++it) {
            float sfv[2], pdfa[2];
            #pragma unroll
            for (int m = 0; m < 2; ++m) {
                f32x2 xv2 = {xv[m], xv[m]};
                f32x2 sfv2 = {0.f, 0.f}, pdfa2 = {0.f, 0.f};
                #pragma unroll
                for (int kk = 0; kk < 4; ++kk) {
                    f32x2 t2 = __builtin_elementwise_fma(xv2, is22[m][kk], nm22[m][kk]);
                    f32x2 e1;
                    e1.x = 1.0f + exp2f_(t2.x);
                    e1.y = 1.0f + exp2f_(t2.y);
                    f32x2 r = { rcpf(e1.x), rcpf(e1.y) };
                    sfv2  = __builtin_elementwise_fma(wt2[m][kk], r, sfv2);
                    f32x2 rr = __builtin_elementwise_fma(-r, r, r);
                    f32x2 wis2v = wt2[m][kk] * is22[m][kk];
                    pdfa2 = __builtin_elementwise_fma(wis2v, rr, pdfa2);
                }
                sfv[m]  = sfv2.x + sfv2.y;
                pdfa[m] = pdfa2.x + pdfa2.y;
            }
            #pragma unroll
            for (int m = 0; m < 2; ++m) {
                float cdf = S[m] - sfv[m];
                float f = (log2f_(cdf) - log2f_(sfv[m])) * LN2_F;
                if (f < yb[m]) lo[m] = xv[m]; else hi[m] = xv[m];
                float step = (f - yb[m]) * cdf * sfv[m] * rcpf(pdfa[m] * SLN2[m]);
                float xn = xv[m] - step;
                if (!(xn > lo[m] && xn < hi[m])) xn = 0.5f * (lo[m] + hi[m]);
                xv[m] = xn;
            }
        }
        // Fused peeled eval: ld + final step.
        {
            float sfv[2], pdfa[2];
            #pragma unroll
            for (int m = 0; m < 2; ++m) {
                f32x2 xv2 = {xv[m], xv[m]};
                f32x2 sfv2 = {0.f, 0.f}, pdfa2 = {0.f, 0.f};
                #pragma unroll
                for (int kk = 0; kk < 4; ++kk) {
                    f32x2 t2 = __builtin_elementwise_fma(xv2, is22[m][kk], nm22[m][kk]);
                    f32x2 e1;
                    e1.x = 1.0f + exp2f_(t2.x);
                    e1.y = 1.0f + exp2f_(t2.y);
                    f32x2 r = { rcpf(e1.x), rcpf(e1.y) };
                    sfv2  = __builtin_elementwise_fma(wt2[m][kk], r, sfv2);
                    f32x2 rr = __builtin_elementwise_fma(-r, r, r);
                    f32x2 wis2v = wt2[m][kk] * is22[m][kk];
                    pdfa2 = __builtin_elementwise_fma(wis2v, rr, pdfa2);
                }
                sfv[m]  = sfv2.x + sfv2.y;
                pdfa[m] = pdfa2.x + pdfa2.y;
            }
            #pragma unroll
            for (int m = 0; m < 2; ++m) {
                float cdf = S[m] - sfv[m];
                float l2c = log2f_(cdf), l2s = log2f_(sfv[m]), l2p = log2f_(pdfa[m]);
                ld[m] = (l2p - l2c - l2s) * LN2_F + LN_LN2_F + lgSn[m];
                float f = (l2c - l2s) * LN2_F;
                if (f < yb[m]) lo[m] = xv[m]; else hi[m] = xv[m];
                float step = (f - yb[m]) * cdf * sfv[m] * rcpf(pdfa[m] * SLN2[m]);
                float xn = xv[m] - step;
                if (!(xn > lo[m] && xn < hi[m])) xn = 0.5f * (lo[m] + hi[m]);
                xv[m] = xn;
            }
        }
    } else {
        // Rare: at least one tail item — solve each independently (exact).
        #pragma unroll 1
        for (int m = 0; m < 2; ++m)
            solve_full(b[m], d, y0[m], hbuf, Wo, bo, xv[m], ld[m], sgn[m]);
    }

    z[(size_t)b[0] * cD + za_off + d] = sgn[0] * xv[0];
    z[(size_t)b[1] * cD + za_off + d] = sgn[1] * xv[1];

    // reduce ld over the 4 waves (4 d's) per b, one atomic per (block, b, m)
    red[0][threadIdx.x] = ld[0];
    red[1][threadIdx.x] = ld[1];
    __syncthreads();
    if (wid == 0) {
        float s0 = red[0][lane] + red[0][lane + 64] + red[0][lane + 128] + red[0][lane + 192];
        atomicAdd(&logq[b0 + lane], s0);
        float s1 = red[1][lane] + red[1][lane + 64] + red[1][lane + 128] + red[1][lane + 192];
        atomicAdd(&logq[b0 + 64 + lane], s1);
    }
}

extern "C" void kernel_launch(void* const* d_in, const int* in_sizes, int n_in,
                              void* d_out, int out_size, void* d_ws, size_t ws_size,
                              hipStream_t stream) {
    const float* x     = (const float*)d_in[0];
    const float* eps   = (const float*)d_in[1];
    const float* W_in  = (const float*)d_in[2];
    const float* b_in  = (const float*)d_in[3];
    const float* W1    = (const float*)d_in[4];
    const float* b1    = (const float*)d_in[5];
    const float* W2    = (const float*)d_in[6];
    const float* b2    = (const float*)d_in[7];
    const float* W_out = (const float*)d_in[8];
    const float* b_out = (const float*)d_in[9];

    float* z    = (float*)d_out;              // (B, D) working state = output z
    float* logq = z + (size_t)cB * cD;        // (B,)   output log_q
    float* hbuf = (float*)d_ws;               // (16, B) transposed scratch

    // Layer schedule (l = 3,2,1,0):
    //   l=3: zb = eps[:, 0:392],  y from eps[:, 392:784], write z[:, 392:784]
    //   l=2: zb = z  [:, 392:784], y from eps[:, 0:392],  write z[:, 0:392]
    //   l=1: zb = z  [:, 0:392],  y from z  [:, 392:784], write z[:, 392:784]
    //   l=0: zb = z  [:, 392:784], y from z  [:, 0:392],  write z[:, 0:392]
    // logq init is folded into mlp(l=3).
    for (int l = cL - 1; l >= 0; --l) {
        const int zb_off = (l & 1) ? 0 : cD1;
        const int za_off = (l & 1) ? cD1 : 0;
        const float* zbsrc = (l == 3) ? (eps + zb_off) : (z + zb_off);
        const float* ysrc  = (l >= 2) ? eps : z;
        mlp_kernel<<<cB / 4, 256, 0, stream>>>(
            zbsrc, x,
            W_in + (size_t)l * cDIN * cH, b_in + (size_t)l * cH,
            W1 + (size_t)l * cR * cH * cH, b1 + (size_t)l * cR * cH,
            W2 + (size_t)l * cR * cH * cH, b2 + (size_t)l * cR * cH,
            hbuf,
            eps, logq, (l == 3) ? 1 : 0);
        invert_kernel<<<dim3(cD1 / 4, cB / 128), 256, 0, stream>>>(
            z, ysrc, hbuf,
            W_out + (size_t)l * cH * cPDIM, b_out + (size_t)l * cPDIM,
            logq, za_off);
    }
}